// Round 14
// baseline (142.622 us; speedup 1.0000x reference)
//
#include <hip/hip_runtime.h>
#include <hip/hip_bf16.h>

#define D 64

typedef __attribute__((ext_vector_type(8))) _Float16 half8;
typedef __attribute__((ext_vector_type(4))) float floatx4;
typedef __attribute__((ext_vector_type(2))) float f32x2;

typedef __attribute__((address_space(1))) unsigned int gu32_t;
typedef __attribute__((address_space(3))) unsigned int lu32_t;

// ---- k_pre: fp16 convert + per-row sq + block partial sum(z^2) + block column sums ----
__global__ __launch_bounds__(256) void k_pre(const float* __restrict__ x, const float* __restrict__ y,
                                             int nx, _Float16* __restrict__ zh,
                                             float* __restrict__ sq, double* __restrict__ Tpart,
                                             float* __restrict__ Spart) {
    int tid = threadIdx.x;
    int lane = tid & 63, wid = tid >> 6;
    int t = blockIdx.x * 256 + tid;             // 8 elements per thread; block = 32 rows
    size_t e = (size_t)t * 8;
    int row = (int)(e >> 6);
    const float* src = (row < nx) ? (x + e) : (y + (e - (size_t)nx * D));
    float4 v0 = ((const float4*)src)[0];
    float4 v1 = ((const float4*)src)[1];
    half8 h;
    h[0]=(_Float16)v0.x; h[1]=(_Float16)v0.y; h[2]=(_Float16)v0.z; h[3]=(_Float16)v0.w;
    h[4]=(_Float16)v1.x; h[5]=(_Float16)v1.y; h[6]=(_Float16)v1.z; h[7]=(_Float16)v1.w;
    *(half8*)(zh + e) = h;
    float p = v0.x*v0.x + v0.y*v0.y + v0.z*v0.z + v0.w*v0.w
            + v1.x*v1.x + v1.y*v1.y + v1.z*v1.z + v1.w*v1.w;
    float s = p;
    s += __shfl_xor(s, 1);
    s += __shfl_xor(s, 2);
    s += __shfl_xor(s, 4);
    if ((tid & 7) == 0) sq[row] = s;

    __shared__ float colbuf[32][64];
    int rib = tid >> 3, cg = tid & 7;
    *(float4*)&colbuf[rib][cg * 8]     = v0;
    *(float4*)&colbuf[rib][cg * 8 + 4] = v1;

    double dp = (double)p;
    dp += __shfl_xor(dp, 1);
    dp += __shfl_xor(dp, 2);
    dp += __shfl_xor(dp, 4);
    dp += __shfl_xor(dp, 8);
    dp += __shfl_xor(dp, 16);
    dp += __shfl_xor(dp, 32);
    __shared__ double redw[4];
    if (lane == 0) redw[wid] = dp;
    __syncthreads();
    if (tid == 0) Tpart[blockIdx.x] = (redw[0] + redw[1]) + (redw[2] + redw[3]);

    if (tid < 64) {
        float cs = 0.f;
#pragma unroll
        for (int r2 = 0; r2 < 32; ++r2) cs += colbuf[r2][tid];
        Spart[blockIdx.x * 64 + tid] = cs;
    }
}

// ---- k_bw: reduce Tpart/Spart -> cq = log2e/(4*bw) ----
__global__ __launch_bounds__(256) void k_bw(const double* __restrict__ Tpart, int ntp,
                                            const float* __restrict__ Spart, int nsp,
                                            int N, float* __restrict__ cq_p) {
    int t = threadIdx.x;
    double Tp = 0.0;
    for (int b = t; b < ntp; b += 256) Tp += Tpart[b];

    int q = t >> 6, col = t & 63;
    int bpq = nsp >> 2;
    const float* sp = Spart + (size_t)(q * bpq) * 64 + col;
    float c0 = 0.f, c1 = 0.f, c2 = 0.f, c3 = 0.f;
    for (int b = 0; b < bpq; b += 4) {
        c0 += sp[(b + 0) * 64];
        c1 += sp[(b + 1) * 64];
        c2 += sp[(b + 2) * 64];
        c3 += sp[(b + 3) * 64];
    }
    __shared__ float cred[256];
    cred[t] = (c0 + c1) + (c2 + c3);

    __shared__ double red[256];
    red[t] = Tp;
    __syncthreads();
    for (int off = 128; off > 0; off >>= 1) {
        if (t < off) red[t] += red[t + off];
        __syncthreads();
    }
    double T = red[0];
    __shared__ double red2[64];
    if (t < 64) {
        float Sk = cred[t] + cred[t + 64] + cred[t + 128] + cred[t + 192];
        red2[t] = (double)Sk * (double)Sk;
    }
    __syncthreads();
    if (t == 0) {
        double S2 = 0.0;
        for (int i = 0; i < 64; ++i) S2 += red2[i];
        double sumd2 = 2.0 * (double)N * T - 2.0 * S2;
        double bw = sumd2 / ((double)N * (double)N - (double)N);
        cq_p[0] = (float)(1.4426950408889634 / (4.0 * bw));
    }
}

// ---- k_mmd: BARRIER-FREE wave-independent jobs ----
// Job J -> (strip s of 32 i-rows, 512-j chunk c). Strips grouped by m=ceil((s+1)/16):
// prefix(m)=8m(m-1), group m = 16 strips x m chunks. Per wave: private LDS 2x4KB dbuf,
// 32-j tiles staged via 4x global_load_lds; per-wave s_waitcnt vmcnt(0) pacing; NO __syncthreads.
__global__ __launch_bounds__(256, 5) void k_mmd(const _Float16* __restrict__ zh,
                                                const float* __restrict__ sq,
                                                const float* __restrict__ cq_p,
                                                int njobs, double* __restrict__ partial) {
    int tid  = threadIdx.x;
    int lane = tid & 63;
    int wid  = tid >> 6;
    int J = (njobs - 1) - ((int)blockIdx.x * 4 + wid);   // longest jobs first

    int m = (int)((1.0f + sqrtf(1.0f + 0.5f * (float)J)) * 0.5f);
    if (m < 1) m = 1;
    while (8 * m * (m + 1) <= J) ++m;
    while (8 * m * (m - 1) > J) --m;
    int r   = J - 8 * m * (m - 1);
    int sig = r / m;
    int c   = r - sig * m;
    int s   = 16 * (m - 1) + sig;          // strip id 0..511

    int i0 = s * 32;
    int jstart = c * 512;
    int width = (s + 1) * 32 - jstart; if (width > 512) width = 512;
    int nt = width >> 5;                   // 1..16 tiles of 32 j
    int diag_j = i0;

    float cq  = cq_p[0];
    f32x2 c2q2 = {2.0f * cq, 2.0f * cq};

    int lrow = lane & 15;
    int c2   = lane >> 4;                  // 0..3

    // A fragments (strip rows i0..i0+31)
    const _Float16* ar0 = zh + (size_t)(i0 + lrow) * D + c2 * 8;
    half8 a00 = *(const half8*)(ar0);
    half8 a01 = *(const half8*)(ar0 + 32);
    half8 a10 = *(const half8*)(ar0 + 16 * D);
    half8 a11 = *(const half8*)(ar0 + 16 * D + 32);

    int irh = c2 * 4;
    f32x2 na[4];
    na[0] = (f32x2){-sq[i0 + irh + 0] * cq, -sq[i0 + irh + 1] * cq};
    na[1] = (f32x2){-sq[i0 + irh + 2] * cq, -sq[i0 + irh + 3] * cq};
    na[2] = (f32x2){-sq[i0 + 16 + irh + 0] * cq, -sq[i0 + 16 + irh + 1] * cq};
    na[3] = (f32x2){-sq[i0 + 16 + irh + 2] * cq, -sq[i0 + 16 + irh + 3] * cq};

    // ---- wave-private LDS double buffer (2 x 4KB) ----
    __shared__ __align__(16) _Float16 bsm[4][2][32 * 64];   // 32 KB total
    char* wbase = (char*)&bsm[wid][0][0];
    // per-lane pre-swizzled global source within a tile (involution cc ^= row&7):
    int lr8 = lane >> 3;                   // row-in-8-group 0..7
    int lc8 = lane & 7;                    // stored chunk slot
    const char* zlane = (const char*)zh + (size_t)jstart * 128 + lr8 * 128 + ((lc8 ^ lr8) * 16);

    auto STAGE = [&](int buf, int t) {
        const char* srcb = zlane + (size_t)t * 4096;
        char* dstb = wbase + buf * 4096;
#pragma unroll
        for (int q = 0; q < 4; ++q)
            __builtin_amdgcn_global_load_lds((const gu32_t*)(const void*)(srcb + q * 1024),
                                             (lu32_t*)(void*)(dstb + q * 1024), 16, 0, 0);
    };

    float acc = 0.f;

    STAGE(0, 0);
    if (nt > 1) STAGE(1, 1);

    for (int t = 0; t < nt; ++t) {
        asm volatile("s_waitcnt vmcnt(0)" ::: "memory");
        __builtin_amdgcn_sched_barrier(0);
        const char* bb = wbase + (t & 1) * 4096;
        int j0t = jstart + t * 32;

        // read both 16-j halves' B frags + sqj first
        half8 b0_0, b1_0, b0_1, b1_1;
        {
            int jr0 = lrow,      sw0 = jr0 & 7;
            int jr1 = 16 + lrow, sw1 = jr1 & 7;
            b0_0 = *(const half8*)(bb + jr0 * 128 + ((c2 ^ sw0) * 16));
            b1_0 = *(const half8*)(bb + jr0 * 128 + (((c2 + 4) ^ sw0) * 16));
            b0_1 = *(const half8*)(bb + jr1 * 128 + ((c2 ^ sw1) * 16));
            b1_1 = *(const half8*)(bb + jr1 * 128 + (((c2 + 4) ^ sw1) * 16));
        }
        float sqj0 = sq[j0t + lrow];
        float sqj1 = sq[j0t + 16 + lrow];
        __builtin_amdgcn_sched_barrier(0);     // reads issued before next STAGE
        if (t + 2 < nt) STAGE(t & 1, t + 2);   // overwrite just-read buffer

#pragma unroll
        for (int si = 0; si < 2; ++si) {
            half8 b0 = si ? b0_1 : b0_0;
            half8 b1 = si ? b1_1 : b1_0;
            float sqj = si ? sqj1 : sqj0;

            floatx4 d0 = {0.f, 0.f, 0.f, 0.f};
            floatx4 d1 = {0.f, 0.f, 0.f, 0.f};
            d0 = __builtin_amdgcn_mfma_f32_16x16x32_f16(a00, b0, d0, 0, 0, 0);
            d0 = __builtin_amdgcn_mfma_f32_16x16x32_f16(a01, b1, d0, 0, 0, 0);
            d1 = __builtin_amdgcn_mfma_f32_16x16x32_f16(a10, b0, d1, 0, 0, 0);
            d1 = __builtin_amdgcn_mfma_f32_16x16x32_f16(a11, b1, d1, 0, 0, 0);

            float nbj = -sqj * cq;
            f32x2 nb2 = {nbj, nbj};
            f32x2 dd[4];
            dd[0] = (f32x2){d0[0], d0[1]};
            dd[1] = (f32x2){d0[2], d0[3]};
            dd[2] = (f32x2){d1[0], d1[1]};
            dd[3] = (f32x2){d1[2], d1[3]};

            f32x2 part2 = {0.f, 0.f};
#pragma unroll
            for (int pk = 0; pk < 4; ++pk) {
                f32x2 u = dd[pk] * c2q2 + (na[pk] + nb2);
                u.x = fminf(u.x, 0.f);
                u.y = fminf(u.y, 0.f);
                f32x2 q;
                q.x = __builtin_amdgcn_exp2f(u.x);
                q.y = __builtin_amdgcn_exp2f(u.y);
                f32x2 m1 = q * q;
                f32x2 m2 = m1 * m1;
                f32x2 m3 = m2 * m2;
                part2 += ((q + m1) + (m2 + m3)) + m3 * m3;
            }
            float wf = ((j0t + si * 16) >= diag_j) ? 1.0f : 2.0f;
            acc = fmaf(part2.x + part2.y, wf, acc);
        }
    }

    // pure wave reduce (f64); lane0 stores — no LDS, no barrier
    double wacc = (double)acc;
    wacc += __shfl_xor(wacc, 1);
    wacc += __shfl_xor(wacc, 2);
    wacc += __shfl_xor(wacc, 4);
    wacc += __shfl_xor(wacc, 8);
    wacc += __shfl_xor(wacc, 16);
    wacc += __shfl_xor(wacc, 32);
    if (lane == 0) partial[J] = wacc;
}

// ---- k_final: classify job partials into XX/XY/YY, finalize ----
__global__ __launch_bounds__(256) void k_final(const double* __restrict__ partial, int njobs,
                                               int nx, int ny, float* __restrict__ out) {
    int t = threadIdx.x;
    double sXX = 0.0, sXY = 0.0, sYY = 0.0;
    for (int p = t; p < njobs; p += 256) {
        int m = (int)((1.0f + sqrtf(1.0f + 0.5f * (float)p)) * 0.5f);
        if (m < 1) m = 1;
        while (8 * m * (m + 1) <= p) ++m;
        while (8 * m * (m - 1) > p) --m;
        int r   = p - 8 * m * (m - 1);
        int sig = r / m;
        int c   = r - sig * m;
        int s   = 16 * (m - 1) + sig;
        double v = partial[p];
        bool iX = s < 256;                 // strip rows < 8192
        bool jX = c < 16;                  // chunk cols < 8192
        if (iX && jX) sXX += v;
        else if (iX != jX) sXY += v;
        else sYY += v;
    }
    __shared__ double r0[256], r1[256], r2[256];
    r0[t] = sXX; r1[t] = sXY; r2[t] = sYY;
    __syncthreads();
    for (int off = 128; off > 0; off >>= 1) {
        if (t < off) {
            r0[t] += r0[t + off];
            r1[t] += r1[t + off];
            r2[t] += r2[t + off];
        }
        __syncthreads();
    }
    if (t == 0) {
        double XX = r0[0] / ((double)nx * (double)nx);
        double XY = r1[0] / (2.0 * (double)nx * (double)ny);
        double YY = r2[0] / ((double)ny * (double)ny);
        out[0] = (float)(XX - 2.0 * XY + YY);
    }
}

extern "C" void kernel_launch(void* const* d_in, const int* in_sizes, int n_in,
                              void* d_out, int out_size, void* d_ws, size_t ws_size,
                              hipStream_t stream) {
    const float* x = (const float*)d_in[0];
    const float* y = (const float*)d_in[1];
    float* out = (float*)d_out;

    int nx = in_sizes[0] / D;     // 8192
    int ny = in_sizes[1] / D;     // 8192
    int N  = nx + ny;             // 16384

    int pre_blocks = (N * D / 8) / 256;    // 512
    int nstrips = N / 32;                  // 512 strips
    int M = nstrips / 16;                  // 32 groups
    int njobs = 8 * M * (M + 1);           // 8448 wave-jobs
    int nblk = njobs / 4;                  // 2112 blocks

    // workspace layout (every buffer fully written before read, every launch)
    char* w = (char*)d_ws;
    double* Tpart   = (double*)(w + 0);        // 512*8    = 4096          -> 4096
    double* partial = (double*)(w + 4096);     // 8448*8   = 67584         -> 71680
    float*  Spart   = (float*) (w + 71680);    // 512*64*4 = 131072        -> 202752
    float*  sq      = (float*) (w + 202752);   // N*4      = 65536         -> 268288
    float*  cq      = (float*) (w + 268288);   // 64 B pad                 -> 268352
    _Float16* zh    = (_Float16*)(w + 268352); // N*64*2   = 2 MiB

    k_pre   <<<pre_blocks, 256, 0, stream>>>(x, y, nx, zh, sq, Tpart, Spart);
    k_bw    <<<1, 256, 0, stream>>>(Tpart, pre_blocks, Spart, pre_blocks, N, cq);
    k_mmd   <<<nblk, 256, 0, stream>>>(zh, sq, cq, njobs, partial);
    k_final <<<1, 256, 0, stream>>>(partial, njobs, nx, ny, out);
}

// Round 15
// 131.300 us; speedup vs baseline: 1.0862x; 1.0862x over previous
//
#include <hip/hip_runtime.h>
#include <hip/hip_bf16.h>

#define D 64

typedef __attribute__((ext_vector_type(8))) _Float16 half8;
typedef __attribute__((ext_vector_type(4))) float floatx4;
typedef __attribute__((ext_vector_type(2))) float f32x2;

typedef __attribute__((address_space(1))) unsigned int gu32_t;
typedef __attribute__((address_space(3))) unsigned int lu32_t;

// ---- k_pre: fp16 convert + per-row sq + f64 atomics for sum(z^2) and column sums ----
__global__ __launch_bounds__(256) void k_pre(const float* __restrict__ x, const float* __restrict__ y,
                                             int nx, _Float16* __restrict__ zh,
                                             float* __restrict__ sq, double* __restrict__ Tsum,
                                             double* __restrict__ colsum) {
    int tid = threadIdx.x;
    int lane = tid & 63, wid = tid >> 6;
    int t = blockIdx.x * 256 + tid;             // 8 elements per thread; block = 32 rows
    size_t e = (size_t)t * 8;
    int row = (int)(e >> 6);
    const float* src = (row < nx) ? (x + e) : (y + (e - (size_t)nx * D));
    float4 v0 = ((const float4*)src)[0];
    float4 v1 = ((const float4*)src)[1];
    half8 h;
    h[0]=(_Float16)v0.x; h[1]=(_Float16)v0.y; h[2]=(_Float16)v0.z; h[3]=(_Float16)v0.w;
    h[4]=(_Float16)v1.x; h[5]=(_Float16)v1.y; h[6]=(_Float16)v1.z; h[7]=(_Float16)v1.w;
    *(half8*)(zh + e) = h;
    float p = v0.x*v0.x + v0.y*v0.y + v0.z*v0.z + v0.w*v0.w
            + v1.x*v1.x + v1.y*v1.y + v1.z*v1.z + v1.w*v1.w;
    float s = p;
    s += __shfl_xor(s, 1);
    s += __shfl_xor(s, 2);
    s += __shfl_xor(s, 4);
    if ((tid & 7) == 0) sq[row] = s;

    __shared__ float colbuf[32][64];
    int rib = tid >> 3, cg = tid & 7;
    *(float4*)&colbuf[rib][cg * 8]     = v0;
    *(float4*)&colbuf[rib][cg * 8 + 4] = v1;

    double dp = (double)p;
    dp += __shfl_xor(dp, 1);
    dp += __shfl_xor(dp, 2);
    dp += __shfl_xor(dp, 4);
    dp += __shfl_xor(dp, 8);
    dp += __shfl_xor(dp, 16);
    dp += __shfl_xor(dp, 32);
    __shared__ double redw[4];
    if (lane == 0) redw[wid] = dp;
    __syncthreads();
    if (tid == 0) atomicAdd(Tsum, (redw[0] + redw[1]) + (redw[2] + redw[3]));

    if (tid < 64) {
        float cs = 0.f;
#pragma unroll
        for (int r2 = 0; r2 < 32; ++r2) cs += colbuf[r2][tid];
        atomicAdd(&colsum[tid], (double)cs);
    }
}

// ---- k_bw: colsum/Tsum -> cq = log2e/(4*bw) (tiny, 1 block) ----
__global__ __launch_bounds__(64) void k_bw(const double* __restrict__ Tsum,
                                           const double* __restrict__ colsum,
                                           int N, float* __restrict__ cq_p) {
    int t = threadIdx.x;
    double Sk = colsum[t];
    double v = Sk * Sk;
    v += __shfl_xor(v, 1);
    v += __shfl_xor(v, 2);
    v += __shfl_xor(v, 4);
    v += __shfl_xor(v, 8);
    v += __shfl_xor(v, 16);
    v += __shfl_xor(v, 32);
    if (t == 0) {
        double T = Tsum[0];
        double sumd2 = 2.0 * (double)N * T - 2.0 * v;
        double bw = sumd2 / ((double)N * (double)N - (double)N);
        cq_p[0] = (float)(1.4426950408889634 / (4.0 * bw));
    }
}

// ---- k_mmd: triangle pass, 3-buffer counted-vmcnt pipeline (T4), 32-j LDS tiles ----
// Per 128-row x <=512-col block: tiles of 32 j staged via 1 gload_lds/wave (pre-swizzled
// global source, linear LDS dest, XOR involution cc^(row&7)); sq[j] cached in LDS (sql) so
// the ONLY in-loop VMEM is STAGE -> counted vmcnt is sound. Loop: STAGE(t+2); compute(t);
// s_waitcnt vmcnt(1) [waits STAGE(t+1), issued a full tile earlier]; sched_barrier; s_barrier.
__global__ __launch_bounds__(256, 8) void k_mmd(const _Float16* __restrict__ zh,
                                                const float* __restrict__ sq,
                                                const float* __restrict__ cq_p,
                                                int nb, double* __restrict__ accs) {
    int bid = (nb - 1) - (int)blockIdx.x;       // longest blocks first
    int g = (int)((sqrtf(1.0f + 2.0f * (float)bid) - 1.0f) * 0.5f);
    while (2 * (g + 1) * (g + 2) <= bid) ++g;
    while (2 * g * (g + 1) > bid) --g;
    int r = bid - 2 * g * (g + 1);
    int gp1 = g + 1;
    int rig = r / gp1;
    int jc  = r - rig * gp1;
    int ib  = 4 * g + rig;

    int jstart = jc * 512;
    int jend   = (ib + 1) * 128;
    if (jend > jstart + 512) jend = jstart + 512;
    int nt = (jend - jstart) >> 5;              // 32-j tiles: nt in {4,8,12,16}
    int diag_j = ib * 128;

    int tid  = threadIdx.x;
    int lane = tid & 63;
    int wid  = tid >> 6;
    int i0 = ib * 128 + wid * 32;

    float cq  = cq_p[0];
    f32x2 c2q2 = {2.0f * cq, 2.0f * cq};

    int lrow = lane & 15;
    int c2   = lane >> 4;                       // chunk index 0..3

    // A fragments (once per block)
    const _Float16* ar0 = zh + (size_t)(i0 + lrow) * D + c2 * 8;
    half8 a00 = *(const half8*)(ar0);
    half8 a01 = *(const half8*)(ar0 + 32);
    half8 a10 = *(const half8*)(ar0 + 16 * D);
    half8 a11 = *(const half8*)(ar0 + 16 * D + 32);

    int irh = c2 * 4;
    f32x2 na[4];
    na[0] = (f32x2){-sq[i0 + irh + 0] * cq, -sq[i0 + irh + 1] * cq};
    na[1] = (f32x2){-sq[i0 + irh + 2] * cq, -sq[i0 + irh + 3] * cq};
    na[2] = (f32x2){-sq[i0 + 16 + irh + 0] * cq, -sq[i0 + 16 + irh + 1] * cq};
    na[3] = (f32x2){-sq[i0 + 16 + irh + 2] * cq, -sq[i0 + 16 + irh + 3] * cq};

    // ---- LDS ----
    __shared__ __align__(16) _Float16 bsm[3][32 * 64];   // 3 x 4KB tile buffers
    __shared__ float sql[512];                           // sq[jstart..jend) cache
    __shared__ double redr[4];

    int width = nt << 5;
    for (int k = tid; k < width; k += 256) sql[k] = sq[jstart + k];

    // staging: 256 threads cover 32 rows x 8 slots of 16B; source chunk pre-swizzled
    int srow = tid >> 3;
    int slot = tid & 7;
    int sc   = slot ^ (srow & 7);
    const char* zlane = (const char*)zh + (size_t)jstart * 128 + srow * 128 + sc * 16;
    char* ldsw = (char*)&bsm[0][0] + wid * 1024;         // wave-uniform dest base

    auto STAGE = [&](int buf, int t) {
        __builtin_amdgcn_global_load_lds((const gu32_t*)(const void*)(zlane + (size_t)t * 4096),
                                         (lu32_t*)(void*)(ldsw + buf * 4096), 16, 0, 0);
    };

    float acc = 0.f;

    STAGE(0, 0);
    STAGE(1, 1);
    __syncthreads();                            // full drain once: buf0,buf1 + sql ready

    int cur = 0;
    for (int t = 0; t < nt; ++t) {
        if (t + 2 < nt) {
            int sbuf = (cur == 0) ? 2 : cur - 1;   // == (t+2)%3
            STAGE(sbuf, t + 2);
        }
        const char* bb = (const char*)&bsm[cur][0];
        int j0t = jstart + t * 32;
#pragma unroll
        for (int s = 0; s < 2; ++s) {
            int jr = s * 16 + lrow;
            int swz = jr & 7;
            half8 b0 = *(const half8*)(bb + jr * 128 + ((c2 ^ swz) * 16));
            half8 b1 = *(const half8*)(bb + jr * 128 + (((c2 + 4) ^ swz) * 16));
            float sqj = sql[t * 32 + s * 16 + lrow];

            floatx4 d0 = {0.f, 0.f, 0.f, 0.f};
            floatx4 d1 = {0.f, 0.f, 0.f, 0.f};
            d0 = __builtin_amdgcn_mfma_f32_16x16x32_f16(a00, b0, d0, 0, 0, 0);
            d0 = __builtin_amdgcn_mfma_f32_16x16x32_f16(a01, b1, d0, 0, 0, 0);
            d1 = __builtin_amdgcn_mfma_f32_16x16x32_f16(a10, b0, d1, 0, 0, 0);
            d1 = __builtin_amdgcn_mfma_f32_16x16x32_f16(a11, b1, d1, 0, 0, 0);

            float nbj = -sqj * cq;
            f32x2 nb2 = {nbj, nbj};
            f32x2 dd[4];
            dd[0] = (f32x2){d0[0], d0[1]};
            dd[1] = (f32x2){d0[2], d0[3]};
            dd[2] = (f32x2){d1[0], d1[1]};
            dd[3] = (f32x2){d1[2], d1[3]};

            f32x2 part2 = {0.f, 0.f};
#pragma unroll
            for (int pk = 0; pk < 4; ++pk) {
                f32x2 u = dd[pk] * c2q2 + (na[pk] + nb2);
                u.x = fminf(u.x, 0.f);
                u.y = fminf(u.y, 0.f);
                f32x2 q;
                q.x = __builtin_amdgcn_exp2f(u.x);
                q.y = __builtin_amdgcn_exp2f(u.y);
                f32x2 m1 = q * q;
                f32x2 m2 = m1 * m1;
                f32x2 m3 = m2 * m2;
                part2 += ((q + m1) + (m2 + m3)) + m3 * m3;
            }
            float wf = ((j0t + s * 16) >= diag_j) ? 1.0f : 2.0f;
            acc = fmaf(part2.x + part2.y, wf, acc);
        }

        if (t + 1 < nt) {
            if (t + 2 < nt) {
                asm volatile("s_waitcnt vmcnt(1)" ::: "memory");   // STAGE(t+1) done; t+2 in flight
            } else {
                asm volatile("s_waitcnt vmcnt(0)" ::: "memory");   // last prefetch: drain
            }
            __builtin_amdgcn_sched_barrier(0);
            __builtin_amdgcn_s_barrier();
        }
        cur = (cur == 2) ? 0 : cur + 1;
    }

    // wave reduce (f64) + block combine + one classified atomic per block
    double wacc = (double)acc;
    wacc += __shfl_xor(wacc, 1);
    wacc += __shfl_xor(wacc, 2);
    wacc += __shfl_xor(wacc, 4);
    wacc += __shfl_xor(wacc, 8);
    wacc += __shfl_xor(wacc, 16);
    wacc += __shfl_xor(wacc, 32);
    if (lane == 0) redr[wid] = wacc;
    __syncthreads();
    if (tid == 0) {
        double tot = (redr[0] + redr[1]) + (redr[2] + redr[3]);
        bool iX = ib < 64;
        bool jX = jc < 16;
        double* tgt = (iX && jX) ? &accs[0] : ((iX != jX) ? &accs[1] : &accs[2]);
        atomicAdd(tgt, tot);
    }
}

// ---- k_fin: finalize from class accumulators ----
__global__ __launch_bounds__(64) void k_fin(const double* __restrict__ accs,
                                            int nx, int ny, float* __restrict__ out) {
    if (threadIdx.x == 0) {
        double XX = accs[0] / ((double)nx * (double)nx);
        double XY = accs[1] / (2.0 * (double)nx * (double)ny);  // weighted mixed = both halves
        double YY = accs[2] / ((double)ny * (double)ny);
        out[0] = (float)(XX - 2.0 * XY + YY);
    }
}

extern "C" void kernel_launch(void* const* d_in, const int* in_sizes, int n_in,
                              void* d_out, int out_size, void* d_ws, size_t ws_size,
                              hipStream_t stream) {
    const float* x = (const float*)d_in[0];
    const float* y = (const float*)d_in[1];
    float* out = (float*)d_out;

    int nx = in_sizes[0] / D;     // 8192
    int ny = in_sizes[1] / D;     // 8192
    int N  = nx + ny;             // 16384

    int pre_blocks = (N * D / 8) / 256;    // 512
    int nT = N / 128;                      // 128 i-tiles
    int ngr = nT / 4;                      // 32 row groups
    int nb = 2 * ngr * (ngr + 1);          // 2112 triangle chunk-blocks

    // workspace layout
    char* w = (char*)d_ws;
    double* accs   = (double*)(w + 0);         // 3 x 8  (XX, XY, YY)
    double* Tsum   = (double*)(w + 24);        // 8
    double* colsum = (double*)(w + 32);        // 64*8 = 512    -> 544
    float*  cq     = (float*) (w + 544);       // pad to 64     -> 608
    float*  sq     = (float*) (w + 608);       // N*4 = 65536   -> 66144
    _Float16* zh   = (_Float16*)(w + 66144);   // N*64*2 = 2 MiB (16B aligned)

    hipMemsetAsync(w, 0, 544, stream);         // zero accs/Tsum/colsum every launch
    k_pre <<<pre_blocks, 256, 0, stream>>>(x, y, nx, zh, sq, Tsum, colsum);
    k_bw  <<<1, 64, 0, stream>>>(Tsum, colsum, N, cq);
    k_mmd <<<nb, 256, 0, stream>>>(zh, sq, cq, nb, accs);
    k_fin <<<1, 64, 0, stream>>>(accs, nx, ny, out);
}